// Round 1
// baseline (359.506 us; speedup 1.0000x reference)
//
#include <hip/hip_runtime.h>
#include <hip/hip_cooperative_groups.h>

namespace cg = cooperative_groups;

// Problem constants
constexpr int cB = 64, cS = 512, cN = 512, cM = 128, cUNF = 6;
constexpr float cDELTA = 0.016666666666666666f;  // DT/UNFOLDS = 0.1/6

// Decomposition: 16 batch-groups (4 batches each) x 16 j-tiles (32 j each).
// Block = 32 j-lanes x 16 i-chunks = 512 threads; grid = 256 blocks (1/CU).
constexpr int KB = 4;                 // batches per group (register-blocked)
constexpr int BG = cB / KB;           // 16
constexpr int JT = 32;                // j per block
constexpr int NJT = cN / JT;          // 16
constexpr int IC = 16;                // i-chunks per block
constexpr int ILEN = cN / IC;         // 32 i per chunk
constexpr int NTHREADS = JT * IC;     // 512
constexpr int NBLOCKS = BG * NJT;     // 256

__device__ __forceinline__ float clamp01(float x) {
    return __builtin_amdgcn_fmed3f(x, 0.0f, 1.0f);
}

template <bool USE_P>
__global__ __launch_bounds__(NTHREADS)
void sns_kernel(const float* __restrict__ inputs, const float* __restrict__ states,
                const float* __restrict__ tau,    const float* __restrict__ bias,
                const float* __restrict__ erev,   const float* __restrict__ wgt,
                const float* __restrict__ sigma,  const float* __restrict__ mu,
                const float* __restrict__ serev,  const float* __restrict__ swgt,
                const float* __restrict__ ssigma, const float* __restrict__ smu,
                const float* __restrict__ mask,   const float* __restrict__ smask,
                const float* __restrict__ inw,    const float* __restrict__ inb,
                const float* __restrict__ outw,   const float* __restrict__ outb,
                float* __restrict__ out, float* __restrict__ ws)
{
    cg::grid_group grid = cg::this_grid();
    const int tid = threadIdx.x;
    const int bid = blockIdx.x;
    const int bg  = bid >> 4;            // / NJT
    const int jt  = bid & (NJT - 1);
    const int b0  = bg * KB;
    const int j0  = jt * JT;
    const int jl  = tid & (JT - 1);      // j within tile (lane-contiguous)
    const int ic  = tid >> 5;            // i-chunk 0..15
    const int j   = j0 + jl;

    float*  vglob = out + cB * cM;       // v state lives in d_out's v-region [B][N]
    float4* P     = (float4*)ws;         // precomputed {a, c, erev*mask, w*mask}[N*N]

    __shared__ float vsh[cN * KB];       // vsh[i*4 + b] : 8 KB
    __shared__ float red[NTHREADS * 8];  // per-thread partials : 16 KB

    // ---- Phase A: precompute packed params (grid-stride) ----
    if constexpr (USE_P) {
        for (int idx = bid * NTHREADS + tid; idx < cN * cN; idx += NBLOCKS * NTHREADS) {
            float sg = sigma[idx];
            float a  = 0.5f / sg;                  // 1/(2*sigma)
            float c  = fmaf(-mu[idx], a, 0.5f);    // 0.5 - mu/(2*sigma)
            float mk = mask[idx];
            P[idx] = make_float4(a, c, erev[idx] * mk, wgt[idx] * mk);
        }
    }

    // ---- Phase B: sensory synapses (once) + v init ----
    // Stage x[b][s] = inputs*in_w + in_b into LDS as xsh[s*4+b]
    for (int t = tid; t < cS * KB; t += NTHREADS) {
        int bb = t >> 9, s = t & (cS - 1);
        vsh[s * KB + bb] = fmaf(inputs[(b0 + bb) * cS + s], inw[s], inb[s]);
    }
    __syncthreads();
    {
        float aR[KB] = {0.f, 0.f, 0.f, 0.f}, aW[KB] = {0.f, 0.f, 0.f, 0.f};
        for (int ii = 0; ii < ILEN; ++ii) {
            int s   = ic * ILEN + ii;
            int idx = s * cN + j;
            float sg = ssigma[idx];
            float a  = 0.5f / sg;
            float c  = fmaf(-smu[idx], a, 0.5f);
            float mk = smask[idx];
            float e  = serev[idx] * mk;
            float wv = swgt[idx] * mk;
            const float4 xv = *(const float4*)&vsh[s * KB];
            float g;
            g = clamp01(fmaf(xv.x, a, c)); aR[0] = fmaf(g, e, aR[0]); aW[0] = fmaf(g, wv, aW[0]);
            g = clamp01(fmaf(xv.y, a, c)); aR[1] = fmaf(g, e, aR[1]); aW[1] = fmaf(g, wv, aW[1]);
            g = clamp01(fmaf(xv.z, a, c)); aR[2] = fmaf(g, e, aR[2]); aW[2] = fmaf(g, wv, aW[2]);
            g = clamp01(fmaf(xv.w, a, c)); aR[3] = fmaf(g, e, aR[3]); aW[3] = fmaf(g, wv, aW[3]);
        }
#pragma unroll
        for (int b = 0; b < KB; ++b) {
            red[tid * 8 + 2 * b]     = aR[b];
            red[tid * 8 + 2 * b + 1] = aW[b];
        }
    }
    __syncthreads();

    // Per-(b,j) state owned by threads tid < 128 for all remaining phases
    float my_srb = 0.f, my_sw = 0.f, my_tau = 1.f, my_ow = 0.f, my_ob = 0.f;
    int   my_gidx = 0, my_jg = 0, my_mi = -1;
    if (tid < JT * KB) {
        int jj = tid & (JT - 1);
        int bb = tid >> 5;
        float r = 0.f, wv = 0.f;
#pragma unroll
        for (int c2 = 0; c2 < IC; ++c2) {
            r  += red[(c2 * JT + jj) * 8 + 2 * bb];
            wv += red[(c2 * JT + jj) * 8 + 2 * bb + 1];
        }
        my_jg   = j0 + jj;
        my_gidx = (b0 + bb) * cN + my_jg;
        my_srb  = r + bias[my_jg];     // s_rev + b, folded
        my_sw   = wv;                  // s_w
        my_tau  = tau[my_jg];
        if (my_jg >= cN - cM) {
            my_mi = my_jg - (cN - cM);
            my_ow = outw[my_mi];
            my_ob = outb[my_mi];
            // out index for this thread:
            my_mi = (b0 + bb) * cM + my_mi;
        }
        vglob[my_gidx] = states[my_gidx];  // v init
    }
    grid.sync();

    // ---- Phase C: 6 unfolds ----
    for (int u = 0; u < cUNF; ++u) {
        // stage v for our 4 batches into LDS as vsh[i*4+b]
        for (int t = tid; t < cN * KB; t += NTHREADS) {
            int bb = t >> 9, i = t & (cN - 1);
            vsh[i * KB + bb] = vglob[(b0 + bb) * cN + i];
        }
        __syncthreads();

        float aR[KB] = {0.f, 0.f, 0.f, 0.f}, aW[KB] = {0.f, 0.f, 0.f, 0.f};
#pragma unroll 4
        for (int ii = 0; ii < ILEN; ++ii) {
            int i   = ic * ILEN + ii;
            int idx = i * cN + j;
            float a, c, e, wv;
            if constexpr (USE_P) {
                float4 p = P[idx];
                a = p.x; c = p.y; e = p.z; wv = p.w;
            } else {
                float sg = sigma[idx];
                a  = 0.5f / sg;
                c  = fmaf(-mu[idx], a, 0.5f);
                float mk = mask[idx];
                e  = erev[idx] * mk;
                wv = wgt[idx]  * mk;
            }
            const float4 vv = *(const float4*)&vsh[i * KB];
            float g;
            g = clamp01(fmaf(vv.x, a, c)); aR[0] = fmaf(g, e, aR[0]); aW[0] = fmaf(g, wv, aW[0]);
            g = clamp01(fmaf(vv.y, a, c)); aR[1] = fmaf(g, e, aR[1]); aW[1] = fmaf(g, wv, aW[1]);
            g = clamp01(fmaf(vv.z, a, c)); aR[2] = fmaf(g, e, aR[2]); aW[2] = fmaf(g, wv, aW[2]);
            g = clamp01(fmaf(vv.w, a, c)); aR[3] = fmaf(g, e, aR[3]); aW[3] = fmaf(g, wv, aW[3]);
        }
#pragma unroll
        for (int b = 0; b < KB; ++b) {
            red[tid * 8 + 2 * b]     = aR[b];
            red[tid * 8 + 2 * b + 1] = aW[b];
        }
        __syncthreads();

        if (tid < JT * KB) {
            int jj = tid & (JT - 1);
            int bb = tid >> 5;
            float r = 0.f, wv = 0.f;
#pragma unroll
            for (int c2 = 0; c2 < IC; ++c2) {
                r  += red[(c2 * JT + jj) * 8 + 2 * bb];
                wv += red[(c2 * JT + jj) * 8 + 2 * bb + 1];
            }
            r  += my_srb;            // + s_rev + b
            wv += my_sw;             // + s_w
            float k    = 1.0f / (1.0f + wv);
            float taun = my_tau * k;
            float inv  = 1.0f / (taun + cDELTA);
            float vold = vsh[my_jg * KB + bb];
            float vn   = (taun * inv) * vold + (cDELTA * inv) * k * r;
            vglob[my_gidx] = vn;     // final unfold writes land in d_out's v-region
            if (u == cUNF - 1 && my_mi >= 0) {
                out[my_mi] = fmaf(vn, my_ow, my_ob);
            }
        }
        grid.sync();
    }
}

extern "C" void kernel_launch(void* const* d_in, const int* in_sizes, int n_in,
                              void* d_out, int out_size, void* d_ws, size_t ws_size,
                              hipStream_t stream)
{
    const float* inputs = (const float*)d_in[0];
    const float* states = (const float*)d_in[1];
    const float* tau    = (const float*)d_in[2];
    const float* bias   = (const float*)d_in[3];
    const float* erev   = (const float*)d_in[4];
    const float* wgt    = (const float*)d_in[5];
    const float* sigma  = (const float*)d_in[6];
    const float* mu     = (const float*)d_in[7];
    const float* serev  = (const float*)d_in[8];
    const float* swgt   = (const float*)d_in[9];
    const float* ssigma = (const float*)d_in[10];
    const float* smu    = (const float*)d_in[11];
    const float* mask   = (const float*)d_in[12];
    const float* smask  = (const float*)d_in[13];
    const float* inw    = (const float*)d_in[14];
    const float* inb    = (const float*)d_in[15];
    const float* outw   = (const float*)d_in[16];
    const float* outb   = (const float*)d_in[17];
    float* out = (float*)d_out;
    float* ws  = (float*)d_ws;

    void* args[] = {(void*)&inputs, (void*)&states, (void*)&tau,   (void*)&bias,
                    (void*)&erev,   (void*)&wgt,    (void*)&sigma, (void*)&mu,
                    (void*)&serev,  (void*)&swgt,   (void*)&ssigma,(void*)&smu,
                    (void*)&mask,   (void*)&smask,  (void*)&inw,   (void*)&inb,
                    (void*)&outw,   (void*)&outb,   (void*)&out,   (void*)&ws};

    const bool use_p = ws_size >= (size_t)cN * cN * sizeof(float4);
    const void* kfn = use_p ? (const void*)sns_kernel<true>
                            : (const void*)sns_kernel<false>;
    hipLaunchCooperativeKernel(kfn, dim3(NBLOCKS), dim3(NTHREADS),
                               args, 0, stream);
}

// Round 2
// 137.125 us; speedup vs baseline: 2.6217x; 2.6217x over previous
//
#include <hip/hip_runtime.h>

// Problem constants
constexpr int cB = 64, cS = 512, cN = 512, cM = 128;
constexpr float cDELTA = 0.016666666666666666f;  // DT/UNFOLDS = 0.1/6

// Decomposition: 16 batch-groups (4 batches) x 16 j-tiles (32 j) = 256 blocks.
// Block = 32 j-lanes x 16 i-chunks = 512 threads.
constexpr int KB = 4;
constexpr int JT = 32;
constexpr int NJT = cN / JT;          // 16
constexpr int IC = 16;
constexpr int ILEN = cN / IC;         // 32
constexpr int NT = JT * IC;           // 512
constexpr int NB = (cB / KB) * NJT;   // 256

__device__ __forceinline__ float clamp01(float x) {
    return __builtin_amdgcn_fmed3f(x, 0.0f, 1.0f);
}

// ---- k_init: pack params into P (float4 {a, c, erev*mask, w*mask}),
//      compute sensory s_rev+b / s_w, copy states -> vA ----
template <bool USE_P>
__global__ __launch_bounds__(NT)
void k_init(const float* __restrict__ inputs, const float* __restrict__ states,
            const float* __restrict__ bias,
            const float* __restrict__ erev,  const float* __restrict__ wgt,
            const float* __restrict__ sigma, const float* __restrict__ mu,
            const float* __restrict__ serev, const float* __restrict__ swgt,
            const float* __restrict__ ssigma,const float* __restrict__ smu,
            const float* __restrict__ mask,  const float* __restrict__ smask,
            const float* __restrict__ inw,   const float* __restrict__ inb,
            float4* __restrict__ P, float* __restrict__ srb,
            float* __restrict__ swS, float* __restrict__ vA)
{
    const int tid = threadIdx.x, bid = blockIdx.x;
    const int bg = bid >> 4, jt = bid & (NJT - 1);
    const int b0 = bg * KB, j0 = jt * JT;
    const int jl = tid & (JT - 1), ic = tid >> 5;
    const int j = j0 + jl;

    __shared__ float xsh[cS * KB];        // 8 KB
    __shared__ float redR[KB * IC * JT];  // 8 KB, lane-contiguous (no conflicts)
    __shared__ float redW[KB * IC * JT];  // 8 KB

    if constexpr (USE_P) {
        for (int idx = bid * NT + tid; idx < cN * cN; idx += NB * NT) {
            float sg = sigma[idx];
            float a  = 0.5f / sg;                 // 1/(2*sigma)
            float c  = fmaf(-mu[idx], a, 0.5f);   // 0.5 - mu/(2*sigma)
            float mk = mask[idx];
            P[idx] = make_float4(a, c, erev[idx] * mk, wgt[idx] * mk);
        }
    }

    // stage x[b][s] = inputs*in_w + in_b as xsh[s*4+b]
    for (int t = tid; t < cS * KB; t += NT) {
        int bb = t >> 9, s = t & (cS - 1);
        xsh[s * KB + bb] = fmaf(inputs[(b0 + bb) * cS + s], inw[s], inb[s]);
    }
    __syncthreads();

    float aR[KB] = {0.f, 0.f, 0.f, 0.f}, aW[KB] = {0.f, 0.f, 0.f, 0.f};
    int idx = (ic * ILEN) * cN + j;
#pragma unroll 8
    for (int ii = 0; ii < ILEN; ++ii, idx += cN) {
        int s    = ic * ILEN + ii;
        float sg = ssigma[idx];
        float a  = 0.5f / sg;
        float c  = fmaf(-smu[idx], a, 0.5f);
        float mk = smask[idx];
        float e  = serev[idx] * mk;
        float wv = swgt[idx] * mk;
        const float4 xv = *(const float4*)&xsh[s * KB];
        float g;
        g = clamp01(fmaf(xv.x, a, c)); aR[0] = fmaf(g, e, aR[0]); aW[0] = fmaf(g, wv, aW[0]);
        g = clamp01(fmaf(xv.y, a, c)); aR[1] = fmaf(g, e, aR[1]); aW[1] = fmaf(g, wv, aW[1]);
        g = clamp01(fmaf(xv.z, a, c)); aR[2] = fmaf(g, e, aR[2]); aW[2] = fmaf(g, wv, aW[2]);
        g = clamp01(fmaf(xv.w, a, c)); aR[3] = fmaf(g, e, aR[3]); aW[3] = fmaf(g, wv, aW[3]);
    }
#pragma unroll
    for (int b = 0; b < KB; ++b) {
        redR[(b * IC + ic) * JT + jl] = aR[b];
        redW[(b * IC + ic) * JT + jl] = aW[b];
    }
    __syncthreads();

    if (tid < JT * KB) {
        int jj = tid & (JT - 1), bb = tid >> 5;
        float r = 0.f, wv = 0.f;
#pragma unroll
        for (int c2 = 0; c2 < IC; ++c2) {
            r  += redR[(bb * IC + c2) * JT + jj];
            wv += redW[(bb * IC + c2) * JT + jj];
        }
        int jg   = j0 + jj;
        int gidx = (b0 + bb) * cN + jg;
        srb[gidx] = r + bias[jg];    // s_rev + b folded
        swS[gidx] = wv;
        vA[gidx]  = states[gidx];
    }
}

// ---- k_unfold: one Euler unfold, vin -> vout ----
template <bool USE_P, bool LAST>
__global__ __launch_bounds__(NT)
void k_unfold(const float* __restrict__ vin, float* __restrict__ vout,
              const float4* __restrict__ P,
              const float* __restrict__ erev,  const float* __restrict__ wgt,
              const float* __restrict__ sigma, const float* __restrict__ mu,
              const float* __restrict__ mask,
              const float* __restrict__ srb,   const float* __restrict__ swS,
              const float* __restrict__ tau,
              const float* __restrict__ outw,  const float* __restrict__ outb,
              float* __restrict__ out)
{
    const int tid = threadIdx.x, bid = blockIdx.x;
    const int bg = bid >> 4, jt = bid & (NJT - 1);
    const int b0 = bg * KB, j0 = jt * JT;
    const int jl = tid & (JT - 1), ic = tid >> 5;
    const int j = j0 + jl;

    __shared__ float vsh[cN * KB];        // 8 KB
    __shared__ float redR[KB * IC * JT];  // 8 KB
    __shared__ float redW[KB * IC * JT];  // 8 KB

    // prefetch epilogue scalars early (latency hidden behind the main loop)
    float my_srb = 0.f, my_sw = 0.f, my_tau = 0.f, my_ow = 0.f, my_ob = 0.f;
    int my_gidx = 0, my_jg = 0, my_mi = -1;
    if (tid < JT * KB) {
        int jj = tid & (JT - 1), bb = tid >> 5;
        my_jg   = j0 + jj;
        my_gidx = (b0 + bb) * cN + my_jg;
        my_srb  = srb[my_gidx];
        my_sw   = swS[my_gidx];
        my_tau  = tau[my_jg];
        if (LAST && my_jg >= cN - cM) {
            int m = my_jg - (cN - cM);
            my_ow = outw[m];
            my_ob = outb[m];
            my_mi = (b0 + bb) * cM + m;
        }
    }

    // stage v for our 4 batches as vsh[i*4+b]
    for (int t = tid; t < cN * KB; t += NT) {
        int bb = t >> 9, i = t & (cN - 1);
        vsh[i * KB + bb] = vin[(b0 + bb) * cN + i];
    }
    __syncthreads();

    float aR[KB] = {0.f, 0.f, 0.f, 0.f}, aW[KB] = {0.f, 0.f, 0.f, 0.f};
    int idx = (ic * ILEN) * cN + j;
    int vo  = (ic * ILEN) * KB;
#pragma unroll 8
    for (int ii = 0; ii < ILEN; ++ii, idx += cN, vo += KB) {
        float a, c, e, wv;
        if constexpr (USE_P) {
            float4 p = P[idx];
            a = p.x; c = p.y; e = p.z; wv = p.w;
        } else {
            float sg = sigma[idx];
            a  = 0.5f / sg;
            c  = fmaf(-mu[idx], a, 0.5f);
            float mk = mask[idx];
            e  = erev[idx] * mk;
            wv = wgt[idx]  * mk;
        }
        const float4 vv = *(const float4*)&vsh[vo];
        float g;
        g = clamp01(fmaf(vv.x, a, c)); aR[0] = fmaf(g, e, aR[0]); aW[0] = fmaf(g, wv, aW[0]);
        g = clamp01(fmaf(vv.y, a, c)); aR[1] = fmaf(g, e, aR[1]); aW[1] = fmaf(g, wv, aW[1]);
        g = clamp01(fmaf(vv.z, a, c)); aR[2] = fmaf(g, e, aR[2]); aW[2] = fmaf(g, wv, aW[2]);
        g = clamp01(fmaf(vv.w, a, c)); aR[3] = fmaf(g, e, aR[3]); aW[3] = fmaf(g, wv, aW[3]);
    }
#pragma unroll
    for (int b = 0; b < KB; ++b) {
        redR[(b * IC + ic) * JT + jl] = aR[b];
        redW[(b * IC + ic) * JT + jl] = aW[b];
    }
    __syncthreads();

    if (tid < JT * KB) {
        int jj = tid & (JT - 1), bb = tid >> 5;
        float r = 0.f, wv = 0.f;
#pragma unroll
        for (int c2 = 0; c2 < IC; ++c2) {
            r  += redR[(bb * IC + c2) * JT + jj];
            wv += redW[(bb * IC + c2) * JT + jj];
        }
        r  += my_srb;
        wv += my_sw;
        float k    = 1.0f / (1.0f + wv);
        float taun = my_tau * k;
        float inv  = 1.0f / (taun + cDELTA);
        float vold = vsh[my_jg * KB + bb];
        float vn   = (taun * inv) * vold + (cDELTA * inv) * k * r;
        vout[my_gidx] = vn;
        if (LAST && my_mi >= 0) out[my_mi] = fmaf(vn, my_ow, my_ob);
    }
}

extern "C" void kernel_launch(void* const* d_in, const int* in_sizes, int n_in,
                              void* d_out, int out_size, void* d_ws, size_t ws_size,
                              hipStream_t stream)
{
    const float* inputs = (const float*)d_in[0];
    const float* states = (const float*)d_in[1];
    const float* tau    = (const float*)d_in[2];
    const float* bias   = (const float*)d_in[3];
    const float* erev   = (const float*)d_in[4];
    const float* wgt    = (const float*)d_in[5];
    const float* sigma  = (const float*)d_in[6];
    const float* mu     = (const float*)d_in[7];
    const float* serev  = (const float*)d_in[8];
    const float* swgt   = (const float*)d_in[9];
    const float* ssigma = (const float*)d_in[10];
    const float* smu    = (const float*)d_in[11];
    const float* mask   = (const float*)d_in[12];
    const float* smask  = (const float*)d_in[13];
    const float* inw    = (const float*)d_in[14];
    const float* inb    = (const float*)d_in[15];
    const float* outw   = (const float*)d_in[16];
    const float* outb   = (const float*)d_in[17];
    float* out = (float*)d_out;
    float* ws  = (float*)d_ws;

    const size_t pfloats = (size_t)cN * cN * 4;              // P as floats
    const bool use_p = ws_size >= (pfloats + 3ull * cB * cN) * sizeof(float);

    float4* P; float* srb; float* swS; float* vB;
    if (use_p) {
        P   = (float4*)ws;
        srb = ws + pfloats;
    } else {
        P   = nullptr;
        srb = ws;
    }
    swS = srb + cB * cN;
    vB  = swS + cB * cN;
    float* vA = out + cB * cM;   // v state region of d_out

    if (use_p) {
        k_init<true><<<NB, NT, 0, stream>>>(inputs, states, bias, erev, wgt, sigma, mu,
                                            serev, swgt, ssigma, smu, mask, smask,
                                            inw, inb, P, srb, swS, vA);
        k_unfold<true, false><<<NB, NT, 0, stream>>>(vA, vB, P, erev, wgt, sigma, mu, mask,
                                                     srb, swS, tau, outw, outb, out);
        k_unfold<true, false><<<NB, NT, 0, stream>>>(vB, vA, P, erev, wgt, sigma, mu, mask,
                                                     srb, swS, tau, outw, outb, out);
        k_unfold<true, false><<<NB, NT, 0, stream>>>(vA, vB, P, erev, wgt, sigma, mu, mask,
                                                     srb, swS, tau, outw, outb, out);
        k_unfold<true, false><<<NB, NT, 0, stream>>>(vB, vA, P, erev, wgt, sigma, mu, mask,
                                                     srb, swS, tau, outw, outb, out);
        k_unfold<true, false><<<NB, NT, 0, stream>>>(vA, vB, P, erev, wgt, sigma, mu, mask,
                                                     srb, swS, tau, outw, outb, out);
        k_unfold<true, true ><<<NB, NT, 0, stream>>>(vB, vA, P, erev, wgt, sigma, mu, mask,
                                                     srb, swS, tau, outw, outb, out);
    } else {
        k_init<false><<<NB, NT, 0, stream>>>(inputs, states, bias, erev, wgt, sigma, mu,
                                             serev, swgt, ssigma, smu, mask, smask,
                                             inw, inb, P, srb, swS, vA);
        k_unfold<false, false><<<NB, NT, 0, stream>>>(vA, vB, P, erev, wgt, sigma, mu, mask,
                                                      srb, swS, tau, outw, outb, out);
        k_unfold<false, false><<<NB, NT, 0, stream>>>(vB, vA, P, erev, wgt, sigma, mu, mask,
                                                      srb, swS, tau, outw, outb, out);
        k_unfold<false, false><<<NB, NT, 0, stream>>>(vA, vB, P, erev, wgt, sigma, mu, mask,
                                                      srb, swS, tau, outw, outb, out);
        k_unfold<false, false><<<NB, NT, 0, stream>>>(vB, vA, P, erev, wgt, sigma, mu, mask,
                                                      srb, swS, tau, outw, outb, out);
        k_unfold<false, false><<<NB, NT, 0, stream>>>(vA, vB, P, erev, wgt, sigma, mu, mask,
                                                      srb, swS, tau, outw, outb, out);
        k_unfold<false, true ><<<NB, NT, 0, stream>>>(vB, vA, P, erev, wgt, sigma, mu, mask,
                                                      srb, swS, tau, outw, outb, out);
    }
}